// Round 1
// baseline (668.208 us; speedup 1.0000x reference)
//
#include <hip/hip_runtime.h>
#include <hip/hip_bf16.h>

// ---------------------------------------------------------------------------
// HierarchicalAffinityLoss: B=8192, D=256 fp32 embeddings, int labels.
// loss = mean over valid rows of relu(maxDot_diff - minDot_same + 0.3)
// where dots are between row-normalized embeddings, same excludes self.
// ---------------------------------------------------------------------------

constexpr int D  = 256;   // embedding dim (fixed by problem)
constexpr int BT = 64;    // Gram tile edge
constexpr int NS = 8;     // column slices (parallelism: (B/BT)*NS blocks)
#define MARGIN 0.3f

// packed family table {0,1,2,1,3,3}, 3 bits each
#define FAM_PACKED 111240   // 0 | 1<<3 | 2<<6 | 1<<9 | 3<<12 | 3<<15

// K1: one wave per row -> rnorm[row] = 1/||E[row]||, fam[row]
__global__ __launch_bounds__(256) void norm_fam_kernel(
    const float* __restrict__ E, const int* __restrict__ labels,
    float* __restrict__ rnorm, int* __restrict__ fam, int B) {
  int row  = blockIdx.x * 4 + (threadIdx.x >> 6);
  int lane = threadIdx.x & 63;
  if (row >= B) return;
  float4 v = *(const float4*)&E[(long)row * D + lane * 4];
  float s = v.x * v.x + v.y * v.y + v.z * v.z + v.w * v.w;
#pragma unroll
  for (int o = 1; o < 64; o <<= 1) s += __shfl_xor(s, o);
  if (lane == 0) {
    rnorm[row] = 1.0f / sqrtf(s);
    int lab = labels[row];
    int labc = lab < 0 ? 0 : (lab > 5 ? 5 : lab);
    fam[row] = (lab < 6) ? ((FAM_PACKED >> (3 * labc)) & 7) : -1;
  }
}

// K2: fused Gram + masked row min/max. Block: 256 threads, 64x64 tile,
// 4x4 dots/thread. LDS tiles stored k-major-ish with XOR swizzle:
// word(col,k) = col*64 + (k ^ (col & 28)); all b128 ops <=2-way conflicts.
__global__ __launch_bounds__(256) void gram_minmax_kernel(
    const float* __restrict__ E, const float* __restrict__ rnorm,
    const int* __restrict__ fam, float* __restrict__ partMin,
    float* __restrict__ partMax, int B) {
  __shared__ float As[BT * BT];
  __shared__ float Bs[BT * BT];

  const int tid = threadIdx.x;
  const int tx = tid & 15;    // col group
  const int ty = tid >> 4;    // row group
  const int rt = blockIdx.x / NS;
  const int s  = blockIdx.x % NS;
  const int r0 = rt * BT;
  const int colsPerSlice = B / NS;
  const int c0base = s * colsPerSlice;
  const int nTiles = colsPerSlice / BT;

  float acc[4][4];
  float minS[4], maxD[4];
  int famR[4];
#pragma unroll
  for (int i = 0; i < 4; ++i) {
    minS[i] = 4.0f;    // dots are in [-1,1]; >=3 means "no same found"
    maxD[i] = -4.0f;   // <=-3 means "no diff found"
    famR[i] = fam[r0 + 4 * ty + i];
#pragma unroll
    for (int j = 0; j < 4; ++j) acc[i][j] = 0.0f;
  }
  const int swa = (ty & 7) << 2;
  const int swb = (tx & 7) << 2;

  for (int t = 0; t < nTiles; ++t) {
    const int c0 = c0base + t * BT;
#pragma unroll 1
    for (int kb = 0; kb < D; kb += BT) {
      __syncthreads();
      // stage 64x64 chunks of A-rows and B-cols (normalize on the fly)
#pragma unroll
      for (int it = 0; it < 4; ++it) {
        int id   = it * 256 + tid;
        int trow = id >> 4;          // 0..63
        int k0   = (id & 15) << 2;   // 0..60
        int sw   = trow * BT + (k0 ^ (trow & 28));
        int ga = r0 + trow;
        float4 va = *(const float4*)&E[(long)ga * D + kb + k0];
        float ra = rnorm[ga];
        va.x *= ra; va.y *= ra; va.z *= ra; va.w *= ra;
        *(float4*)&As[sw] = va;
        int gb = c0 + trow;
        float4 vb = *(const float4*)&E[(long)gb * D + kb + k0];
        float rb = rnorm[gb];
        vb.x *= rb; vb.y *= rb; vb.z *= rb; vb.w *= rb;
        *(float4*)&Bs[sw] = vb;
      }
      __syncthreads();
      // inner: 16 x (8 ds_read_b128 + 64 fma)
#pragma unroll
      for (int k = 0; k < BT; k += 4) {
        float4 a[4], b[4];
#pragma unroll
        for (int i = 0; i < 4; ++i)
          a[i] = *(const float4*)&As[(4 * ty + i) * BT + (k ^ swa)];
#pragma unroll
        for (int j = 0; j < 4; ++j)
          b[j] = *(const float4*)&Bs[(4 * tx + j) * BT + (k ^ swb)];
#pragma unroll
        for (int i = 0; i < 4; ++i)
#pragma unroll
          for (int j = 0; j < 4; ++j) {
            float c = acc[i][j];
            c = fmaf(a[i].x, b[j].x, c);
            c = fmaf(a[i].y, b[j].y, c);
            c = fmaf(a[i].z, b[j].z, c);
            c = fmaf(a[i].w, b[j].w, c);
            acc[i][j] = c;
          }
      }
    }
    // epilogue for this 64x64 tile: masked min/max updates
#pragma unroll
    for (int j = 0; j < 4; ++j) {
      int gc = c0 + 4 * tx + j;
      int fc = fam[gc];
#pragma unroll
      for (int i = 0; i < 4; ++i) {
        float d = acc[i][j];
        acc[i][j] = 0.0f;
        int gr = r0 + 4 * ty + i;
        int fr = famR[i];
        bool vr = fr >= 0, vc = fc >= 0;
        if (vr && fr == fc && gr != gc) minS[i] = fminf(minS[i], d);
        if (vr && vc && fr != fc)       maxD[i] = fmaxf(maxD[i], d);
      }
    }
  }
  // reduce across the 16 tx lanes sharing the same 4 rows (same wave)
#pragma unroll
  for (int o = 1; o < 16; o <<= 1) {
#pragma unroll
    for (int i = 0; i < 4; ++i) {
      minS[i] = fminf(minS[i], __shfl_xor(minS[i], o));
      maxD[i] = fmaxf(maxD[i], __shfl_xor(maxD[i], o));
    }
  }
  if (tx == 0) {
#pragma unroll
    for (int i = 0; i < 4; ++i) {
      int gr = r0 + 4 * ty + i;
      partMin[(long)s * B + gr] = minS[i];
      partMax[(long)s * B + gr] = maxD[i];
    }
  }
}

// K3: combine NS slices per row, compute mean loss over valid rows.
__global__ __launch_bounds__(256) void finalize_kernel(
    const float* __restrict__ partMin, const float* __restrict__ partMax,
    float* __restrict__ out, int B) {
  __shared__ float ssum[4];
  __shared__ int   scnt[4];
  float sum = 0.0f;
  int cnt = 0;
  for (int r = threadIdx.x; r < B; r += 256) {
    float m = 4.0f, M = -4.0f;
#pragma unroll
    for (int s = 0; s < NS; ++s) {
      m = fminf(m, partMin[(long)s * B + r]);
      M = fmaxf(M, partMax[(long)s * B + r]);
    }
    if (m < 3.0f && M > -3.0f) {  // has same && has diff (row validity implied)
      sum += fmaxf(M - m + MARGIN, 0.0f);
      cnt += 1;
    }
  }
#pragma unroll
  for (int o = 1; o < 64; o <<= 1) {
    sum += __shfl_xor(sum, o);
    cnt += __shfl_xor(cnt, o);
  }
  int wave = threadIdx.x >> 6;
  if ((threadIdx.x & 63) == 0) { ssum[wave] = sum; scnt[wave] = cnt; }
  __syncthreads();
  if (threadIdx.x == 0) {
    float S = 0.0f; int C = 0;
#pragma unroll
    for (int w = 0; w < 4; ++w) { S += ssum[w]; C += scnt[w]; }
    out[0] = S / (float)(C > 0 ? C : 1);
  }
}

extern "C" void kernel_launch(void* const* d_in, const int* in_sizes, int n_in,
                              void* d_out, int out_size, void* d_ws, size_t ws_size,
                              hipStream_t stream) {
  const float* E      = (const float*)d_in[0];
  const int*   labels = (const int*)d_in[1];
  float*       out    = (float*)d_out;

  const int B = in_sizes[1];  // 8192 (in_sizes[0] / D)

  // workspace layout: rnorm[B] | fam[B] | partMin[NS*B] | partMax[NS*B]
  float* rnorm   = (float*)d_ws;
  int*   fam     = (int*)(rnorm + B);
  float* partMin = (float*)(fam + B);
  float* partMax = partMin + (long)NS * B;

  norm_fam_kernel<<<dim3((B + 3) / 4), 256, 0, stream>>>(E, labels, rnorm, fam, B);
  gram_minmax_kernel<<<dim3((B / BT) * NS), 256, 0, stream>>>(E, rnorm, fam,
                                                              partMin, partMax, B);
  finalize_kernel<<<1, 256, 0, stream>>>(partMin, partMax, out, B);
}

// Round 3
// 166.186 us; speedup vs baseline: 4.0209x; 4.0209x over previous
//
#include <hip/hip_runtime.h>
#include <hip/hip_bf16.h>

// ---------------------------------------------------------------------------
// HierarchicalAffinityLoss on MI355X, fp16-MFMA path.
// loss = mean_r relu(maxDot_diff(r) - minDot_same(r) + 0.3), dots of
// row-normalized embeddings. Self-exclusion dropped: self-dot == 1.0 can
// never be the min over ~2000 same-family dots clustered near 0.
// Round-3 fixes: (a) cross-wave partial-write race (two waves share rows ->
// combine via LDS before writing), (b) bf16 -> fp16 fragments for ~8x less
// rounding noise at the same MFMA rate.
// ---------------------------------------------------------------------------

typedef __attribute__((ext_vector_type(8))) _Float16 half8;  // MFMA A/B frag
typedef __attribute__((ext_vector_type(4))) float floatx4;   // MFMA C/D
typedef __attribute__((ext_vector_type(4))) unsigned short ushort4v;

constexpr int D  = 256;  // embedding dim
constexpr int NS = 16;   // column slices: grid = (B/128)*NS = 1024 blocks
#define MARGIN 0.3f
// packed family table {0,1,2,1,3,3}, 3 bits each
#define FAM_PACKED 111240

// K1: one wave per row -> Eh[row][:] = fp16(E/||E||), fam[row]
__global__ __launch_bounds__(256) void prep_kernel(
    const float* __restrict__ E, const int* __restrict__ labels,
    unsigned short* __restrict__ Eh, int* __restrict__ fam, int B) {
  int row  = blockIdx.x * 4 + (threadIdx.x >> 6);
  int lane = threadIdx.x & 63;
  if (row >= B) return;
  float4 v = *(const float4*)&E[(long)row * D + lane * 4];
  float s = v.x * v.x + v.y * v.y + v.z * v.z + v.w * v.w;
#pragma unroll
  for (int o = 1; o < 64; o <<= 1) s += __shfl_xor(s, o);
  float rn = 1.0f / sqrtf(s);   // exact fp32, matches reference normalize
  ushort4v o4;
  o4.x = __builtin_bit_cast(unsigned short, (_Float16)(v.x * rn));
  o4.y = __builtin_bit_cast(unsigned short, (_Float16)(v.y * rn));
  o4.z = __builtin_bit_cast(unsigned short, (_Float16)(v.z * rn));
  o4.w = __builtin_bit_cast(unsigned short, (_Float16)(v.w * rn));
  *(ushort4v*)&Eh[(long)row * D + lane * 4] = o4;
  if (lane == 0) {
    int lab = labels[row];
    int labc = lab < 0 ? 0 : (lab > 5 ? 5 : lab);
    fam[row] = (lab < 6) ? ((FAM_PACKED >> (3 * labc)) & 7) : -1;
  }
}

// K2: MFMA Gram (never materialized) + fused masked row min/max.
// Block = 256 threads (4 waves, 2x2), tile 128x128, BK=64, 16x16x32 f16.
// LDS layout: row-major [128][64] fp16, 16B chunk index XOR-swizzled by
// (row&7) -> all b128 reads/writes sit at the wave64 LDS floor (<=2-way).
__global__ __launch_bounds__(256) void gram_mfma_kernel(
    const unsigned short* __restrict__ Eh, const int* __restrict__ fam,
    float* __restrict__ partMin, float* __restrict__ partMax, int B) {
  __shared__ unsigned short As[128 * 64];   // 16 KB
  __shared__ unsigned short Bs[128 * 64];   // 16 KB
  __shared__ float sMin[256];               // [col-half][128 rows]
  __shared__ float sMax[256];

  const int tid = threadIdx.x;
  const int l   = tid & 63;
  const int wid = tid >> 6;
  const int wy  = wid >> 1, wx = wid & 1;   // 2x2 wave grid, 64x64 each
  const int m   = l & 15, q = l >> 4, sel = l & 7;

  const int rt = blockIdx.x / NS, s = blockIdx.x % NS;
  const int r0 = rt * 128;
  const int colsPerSlice = B / NS;          // 512
  const int c0base = s * colsPerSlice;

  float minS[16], maxD[16];
  int famR[16];
#pragma unroll
  for (int i = 0; i < 16; ++i) { minS[i] = 4.0f; maxD[i] = -4.0f; }
#pragma unroll
  for (int mi = 0; mi < 4; ++mi)
#pragma unroll
    for (int r = 0; r < 4; ++r)
      famR[mi * 4 + r] = fam[r0 + wy * 64 + mi * 16 + q * 4 + r];

  floatx4 acc[4][4];
#pragma unroll
  for (int mi = 0; mi < 4; ++mi)
#pragma unroll
    for (int nj = 0; nj < 4; ++nj) acc[mi][nj] = (floatx4)0.0f;

  for (int ct = 0; ct < colsPerSlice / 128; ++ct) {
    const int ctile0 = c0base + ct * 128;
#pragma unroll 1
    for (int kb = 0; kb < D; kb += 64) {
      __syncthreads();
      // stage A rows + B rows (cols of the Gram), 16B per thread-iter
#pragma unroll
      for (int it = 0; it < 4; ++it) {
        int id  = it * 256 + tid;
        int row = id >> 3, kc = id & 7;
        int sw  = row * 64 + ((kc ^ (row & 7)) << 3);
        *(half8*)&As[sw] =
            *(const half8*)&Eh[(long)(r0 + row) * D + kb + kc * 8];
        *(half8*)&Bs[sw] =
            *(const half8*)&Eh[(long)(ctile0 + row) * D + kb + kc * 8];
      }
      __syncthreads();
#pragma unroll
      for (int kh = 0; kh < 2; ++kh) {       // two k=32 steps per BK=64
        const int lc = kh * 4 + q;           // logical 16B chunk for this quad
        half8 a[4], b[4];
#pragma unroll
        for (int mi = 0; mi < 4; ++mi)
          a[mi] = *(const half8*)
              &As[(wy * 64 + mi * 16 + m) * 64 + ((lc ^ sel) << 3)];
#pragma unroll
        for (int nj = 0; nj < 4; ++nj)
          b[nj] = *(const half8*)
              &Bs[(wx * 64 + nj * 16 + m) * 64 + ((lc ^ sel) << 3)];
#pragma unroll
        for (int mi = 0; mi < 4; ++mi)
#pragma unroll
          for (int nj = 0; nj < 4; ++nj)
            acc[mi][nj] = __builtin_amdgcn_mfma_f32_16x16x32_f16(
                a[mi], b[nj], acc[mi][nj], 0, 0, 0);
      }
    }
    // fused epilogue: masked min/max for this 128x128 tile
    int famC[4];
#pragma unroll
    for (int nj = 0; nj < 4; ++nj)
      famC[nj] = fam[ctile0 + wx * 64 + nj * 16 + m];
#pragma unroll
    for (int mi = 0; mi < 4; ++mi)
#pragma unroll
      for (int nj = 0; nj < 4; ++nj) {
#pragma unroll
        for (int r = 0; r < 4; ++r) {
          float d = acc[mi][nj][r];          // C/D: col=l&15, row=q*4+r
          bool same = (famR[mi * 4 + r] == famC[nj]);
          minS[mi * 4 + r] = fminf(minS[mi * 4 + r], same ? d : 4.0f);
          maxD[mi * 4 + r] = fmaxf(maxD[mi * 4 + r], same ? -4.0f : d);
        }
        acc[mi][nj] = (floatx4)0.0f;
      }
  }
  // reduce across the 16 lanes (same q, different col index m)
#pragma unroll
  for (int o = 1; o < 16; o <<= 1)
#pragma unroll
    for (int i = 0; i < 16; ++i) {
      minS[i] = fminf(minS[i], __shfl_xor(minS[i], o));
      maxD[i] = fmaxf(maxD[i], __shfl_xor(maxD[i], o));
    }
  // combine the two column-half waves per row via LDS (race fix), then write
  if (m == 0) {
#pragma unroll
    for (int mi = 0; mi < 4; ++mi)
#pragma unroll
      for (int r = 0; r < 4; ++r) {
        int lr = wy * 64 + mi * 16 + q * 4 + r;   // 0..127
        sMin[wx * 128 + lr] = minS[mi * 4 + r];
        sMax[wx * 128 + lr] = maxD[mi * 4 + r];
      }
  }
  __syncthreads();
  if (tid < 128) {
    float mn = fminf(sMin[tid], sMin[128 + tid]);
    float mx = fmaxf(sMax[tid], sMax[128 + tid]);
    partMin[(long)s * B + r0 + tid] = mn;
    partMax[(long)s * B + r0 + tid] = mx;
  }
}

// K3: combine NS slices per row, mean loss over valid rows.
__global__ __launch_bounds__(256) void finalize_kernel(
    const float* __restrict__ partMin, const float* __restrict__ partMax,
    float* __restrict__ out, int B) {
  __shared__ float ssum[4];
  __shared__ int   scnt[4];
  float sum = 0.0f;
  int cnt = 0;
  for (int r = threadIdx.x; r < B; r += 256) {
    float mn = 4.0f, mx = -4.0f;
#pragma unroll
    for (int s = 0; s < NS; ++s) {
      mn = fminf(mn, partMin[(long)s * B + r]);
      mx = fmaxf(mx, partMax[(long)s * B + r]);
    }
    if (mn < 3.0f && mx > -3.0f) {   // has same && has diff
      sum += fmaxf(mx - mn + MARGIN, 0.0f);
      cnt += 1;
    }
  }
#pragma unroll
  for (int o = 1; o < 64; o <<= 1) {
    sum += __shfl_xor(sum, o);
    cnt += __shfl_xor(cnt, o);
  }
  int wave = threadIdx.x >> 6;
  if ((threadIdx.x & 63) == 0) { ssum[wave] = sum; scnt[wave] = cnt; }
  __syncthreads();
  if (threadIdx.x == 0) {
    float S = 0.0f; int C = 0;
#pragma unroll
    for (int w = 0; w < 4; ++w) { S += ssum[w]; C += scnt[w]; }
    out[0] = S / (float)(C > 0 ? C : 1);
  }
}

extern "C" void kernel_launch(void* const* d_in, const int* in_sizes, int n_in,
                              void* d_out, int out_size, void* d_ws, size_t ws_size,
                              hipStream_t stream) {
  const float* E      = (const float*)d_in[0];
  const int*   labels = (const int*)d_in[1];
  float*       out    = (float*)d_out;
  const int B = in_sizes[1];   // 8192

  // ws: Eh[B*D] fp16 | fam[B] | partMin[NS*B] | partMax[NS*B]  (~5.1 MB)
  unsigned short* Eh = (unsigned short*)d_ws;
  int* fam           = (int*)(Eh + (size_t)B * D);
  float* partMin     = (float*)(fam + B);
  float* partMax     = partMin + (size_t)NS * B;

  prep_kernel<<<dim3(B / 4), 256, 0, stream>>>(E, labels, Eh, fam, B);
  gram_mfma_kernel<<<dim3((B / 128) * NS), 256, 0, stream>>>(Eh, fam,
                                                             partMin, partMax, B);
  finalize_kernel<<<1, 256, 0, stream>>>(partMin, partMax, out, B);
}